// Round 8
// baseline (108.178 us; speedup 1.0000x reference)
//
#include <hip/hip_runtime.h>
#include <hip/hip_bf16.h>

#define T_TOK 8192
#define DDIM  1024
#define NEXP  8
#define NT    32   // K-tiles of 32

typedef __attribute__((ext_vector_type(8))) short bf16x8;
typedef __attribute__((ext_vector_type(4))) float f32x4;

__device__ inline unsigned short f2bf(float f) {
  union { float f; unsigned int u; } a; a.f = f;
  unsigned int u = a.u;
  unsigned int r = (u + 0x7fffu + ((u >> 16) & 1u)) >> 16;  // RNE
  return (unsigned short)r;
}

__device__ inline float bf2f(unsigned short u) {
  union { unsigned int u; float f; } a; a.u = ((unsigned int)u) << 16;
  return a.f;
}

__device__ inline void gload_lds16(const void* g, void* l) {
  __builtin_amdgcn_global_load_lds(
      (const __attribute__((address_space(1))) void*)g,
      (__attribute__((address_space(3))) void*)l, 16, 0, 0);
}

// ---------------- fused prep: blocks [0,2048) gate+cast-x, [2048,10240) cast W --
__global__ __launch_bounds__(256) void prep_kernel(
    const float* __restrict__ x, const float* __restrict__ gw,
    const float* __restrict__ ew,
    unsigned short* __restrict__ xb, unsigned short* __restrict__ Wb,
    int* __restrict__ e_of, float* __restrict__ w_of) {
  if (blockIdx.x >= 2048) {
    int i = (blockIdx.x - 2048) * 256 + threadIdx.x;   // < 2097152
    float4 v = reinterpret_cast<const float4*>(ew)[i];
    ushort4 o;
    o.x = f2bf(v.x); o.y = f2bf(v.y); o.z = f2bf(v.z); o.w = f2bf(v.w);
    reinterpret_cast<ushort4*>(Wb)[i] = o;
    return;
  }
  int t = blockIdx.x * 4 + (threadIdx.x >> 6);
  int lane = threadIdx.x & 63;
  const float4* xr = reinterpret_cast<const float4*>(x + (size_t)t * DDIM);
  ushort4* xbr = reinterpret_cast<ushort4*>(xb + (size_t)t * DDIM);
  float acc[NEXP];
#pragma unroll
  for (int e = 0; e < NEXP; ++e) acc[e] = 0.f;
#pragma unroll
  for (int c = 0; c < 4; ++c) {
    float4 xv = xr[c * 64 + lane];
    ushort4 o;
    o.x = f2bf(xv.x); o.y = f2bf(xv.y); o.z = f2bf(xv.z); o.w = f2bf(xv.w);
    xbr[c * 64 + lane] = o;
#pragma unroll
    for (int e = 0; e < NEXP; ++e) {
      float4 g = reinterpret_cast<const float4*>(gw + e * DDIM)[c * 64 + lane];
      acc[e] += xv.x * g.x + xv.y * g.y + xv.z * g.z + xv.w * g.w;
    }
  }
#pragma unroll
  for (int e = 0; e < NEXP; ++e) {
#pragma unroll
    for (int s = 32; s > 0; s >>= 1) acc[e] += __shfl_xor(acc[e], s);
  }
  if (lane == 0) {
    int e0 = 0; float v0 = acc[0];
#pragma unroll
    for (int e = 1; e < NEXP; ++e) if (acc[e] > v0) { v0 = acc[e]; e0 = e; }
    int e1 = (e0 == 0) ? 1 : 0; float v1 = acc[e1];
#pragma unroll
    for (int e = 0; e < NEXP; ++e)
      if (e != e0 && acc[e] > v1) { v1 = acc[e]; e1 = e; }
    float w1 = 1.f / (1.f + expf(v0 - v1));
    float w0 = 1.f - w1;
    e_of[2 * t] = e0; e_of[2 * t + 1] = e1;
    w_of[2 * t] = w0; w_of[2 * t + 1] = w1;
  }
}

// ---------------- counts: LDS histogram, 8 global atomics per block ----------------
__global__ __launch_bounds__(512) void count_kernel(
    const int* __restrict__ e_of, int* __restrict__ counts) {
  __shared__ int lc[NEXP];
  int tid = threadIdx.x;
  if (tid < NEXP) lc[tid] = 0;
  __syncthreads();
  atomicAdd(&lc[e_of[blockIdx.x * 512 + tid]], 1);
  __syncthreads();
  if (tid < NEXP) atomicAdd(&counts[tid], lc[tid]);
}

// ---------------- scan + block map (BM = 128) ----------------
__global__ void scan_kernel(const int* __restrict__ counts,
                            int* __restrict__ offs, int* __restrict__ cursor,
                            int* __restrict__ nblk, int* __restrict__ blkmap) {
  if (threadIdx.x == 0) {
    int s = 0;
    for (int e = 0; e < NEXP; ++e) { offs[e] = s; cursor[e] = s; s += counts[e]; }
    int nb = 0;
    for (int e = 0; e < NEXP; ++e) {
      int mb = (counts[e] + 127) >> 7;
      for (int j = 0; j < mb; ++j) blkmap[nb++] = (e << 8) | j;
    }
    nblk[0] = nb;
  }
}

// ---------------- build row lists: block-aggregated cursor atomics ----------------
__global__ __launch_bounds__(256) void build_kernel(
    const int* __restrict__ e_of, int* __restrict__ cursor,
    int* __restrict__ row_src, int* __restrict__ tok_row) {
  __shared__ int lc[NEXP];
  __shared__ int lbase[NEXP];
  int tid = threadIdx.x;
  if (tid < NEXP) lc[tid] = 0;
  __syncthreads();
  int i0 = blockIdx.x * 512 + tid;
  int i1 = i0 + 256;
  int ea = e_of[i0], eb = e_of[i1];
  int ra = atomicAdd(&lc[ea], 1);
  int rb = atomicAdd(&lc[eb], 1);
  __syncthreads();
  if (tid < NEXP) lbase[tid] = atomicAdd(&cursor[tid], lc[tid]);
  __syncthreads();
  int pa = lbase[ea] + ra;
  int pb = lbase[eb] + rb;
  row_src[pa] = i0 >> 1;
  tok_row[i0] = pa;
  row_src[pb] = i1 >> 1;
  tok_row[i1] = pb;
}

// ---------------- grouped GEMM: 128x128 tile, BK=32, 4 waves (2Mx2N) ------------
// Double-buffered BK=32 ring: 32 KB LDS total -> 4 blocks/CU (m97 cross-block
// overlap) AND counted vmcnt(4) gate (R6-proven race-free order: issue t+1,
// wait tile t, barrier, compute, barrier) — load latency never exposed.
// BK=32 swizzle (4 x 16B slots/row): slot = c ^ ((row>>2)&3). Over 16 aligned
// rows, (row&3,(row>>2)&3) covers all 16 combos -> 2-way bank access = free.
// Stage-side inverse on the per-lane GLOBAL address: cperm = ((l&3)^((l>>4)&3))*8.
__global__ __launch_bounds__(256, 4) void gemm_kernel(
    const unsigned short* __restrict__ xb, const unsigned short* __restrict__ Wb,
    const int* __restrict__ row_src, const int* __restrict__ counts,
    const int* __restrict__ offs, const int* __restrict__ nblk,
    const int* __restrict__ blkmap, unsigned short* __restrict__ Yb) {
  // bijective XCD swizzle: 1080 = 8 * 135; consecutive wg share one XCD's L2.
  int orig = blockIdx.x;
  int wg = (orig & 7) * 135 + (orig >> 3);
  int mi = wg >> 3, ni = wg & 7;
  if (mi >= nblk[0]) return;
  int em = blkmap[mi];
  int e = em >> 8, mj = em & 255;
  int ce = counts[e];
  int base = offs[e];
  int m0 = mj << 7;    // 128-row m-block
  int n0 = ni << 7;    // 128-col n-block

  __shared__ unsigned short As[2][128 * 32];  // 16 KB
  __shared__ unsigned short Bs[2][128 * 32];  // 16 KB

  int tid = threadIdx.x;
  int lane = tid & 63;
  int wid = tid >> 6;          // 0..3
  int wr = wid >> 1, wc = wid & 1;   // 2(M) x 2(N), wave tile 64x64

  // staging: per tile each wave issues 2 A-loads + 2 B-loads (1 KB each,
  // 16 rows of 64 B). Wave wid owns row-chunks wid*2+j.
  int rl = lane >> 2;                 // 0..15 row within chunk
  int cperm = ((lane & 3) ^ ((lane >> 4) & 3)) * 8;  // pre-swizzled element off
  const unsigned short* We = Wb + (size_t)e * DDIM * DDIM;
  const unsigned short* asrc[2];
  const unsigned short* bsrc[2];
#pragma unroll
  for (int j = 0; j < 2; ++j) {
    int row = (wid * 2 + j) * 16 + rl;     // [0,128)
    int i = m0 + row; if (i > ce - 1) i = ce - 1;
    int tk = row_src[base + i];
    asrc[j] = xb + (size_t)tk * DDIM + cperm;
    bsrc[j] = We + (size_t)(n0 + row) * DDIM + cperm;
  }

  f32x4 acc[4][4];
#pragma unroll
  for (int m = 0; m < 4; ++m)
#pragma unroll
    for (int n = 0; n < 4; ++n) acc[m][n] = (f32x4){0.f, 0.f, 0.f, 0.f};

  int frow_a = wr * 64 + (lane & 15);
  int frow_b = wc * 64 + (lane & 15);
  int fchunk = lane >> 4;            // 0..3 = logical 16B chunk (8 shorts)

  // prologue: stage tile 0 -> buf0 (4 loads/wave)
#pragma unroll
  for (int j = 0; j < 2; ++j) {
    gload_lds16(asrc[j], &As[0][(wid * 2 + j) * 512]);
    gload_lds16(bsrc[j], &Bs[0][(wid * 2 + j) * 512]);
  }

  for (int t = 0; t < NT; ++t) {
    int b = t & 1;
    if (t + 1 < NT) {
      // issue tile t+1 into other buffer (its last readers synced at the
      // end-of-iter barrier of t-1), THEN gate on tile t's loads.
      int koff = (t + 1) * 32;
      unsigned short* Ad = &As[b ^ 1][0];
      unsigned short* Bd = &Bs[b ^ 1][0];
#pragma unroll
      for (int j = 0; j < 2; ++j) {
        gload_lds16(asrc[j] + koff, Ad + (wid * 2 + j) * 512);
        gload_lds16(bsrc[j] + koff, Bd + (wid * 2 + j) * 512);
      }
      asm volatile("s_waitcnt vmcnt(4)" ::: "memory");  // tile t landed
    } else {
      asm volatile("s_waitcnt vmcnt(0)" ::: "memory");  // final drain
    }
    __builtin_amdgcn_s_barrier();
    asm volatile("" ::: "memory");

    const unsigned short* Ar = &As[b][0];
    const unsigned short* Br = &Bs[b][0];
    bf16x8 af[4], bfr[4];
#pragma unroll
    for (int m = 0; m < 4; ++m) {
      int row = frow_a + m * 16;
      af[m] = *reinterpret_cast<const bf16x8*>(
          &Ar[row * 32 + ((fchunk ^ ((row >> 2) & 3)) << 3)]);
    }
#pragma unroll
    for (int n = 0; n < 4; ++n) {
      int row = frow_b + n * 16;
      bfr[n] = *reinterpret_cast<const bf16x8*>(
          &Br[row * 32 + ((fchunk ^ ((row >> 2) & 3)) << 3)]);
    }
    __builtin_amdgcn_s_setprio(1);
#pragma unroll
    for (int m = 0; m < 4; ++m)
#pragma unroll
      for (int n = 0; n < 4; ++n)
        acc[m][n] = __builtin_amdgcn_mfma_f32_16x16x32_bf16(af[m], bfr[n], acc[m][n], 0, 0, 0);
    __builtin_amdgcn_s_setprio(0);

    asm volatile("" ::: "memory");
    __builtin_amdgcn_s_barrier();   // all waves done reading buf b
  }

  // epilogue: C/D layout col=lane&15, row=(lane>>4)*4+reg
  int crow = (lane >> 4) * 4;
  int ccol = lane & 15;
#pragma unroll
  for (int m = 0; m < 4; ++m) {
#pragma unroll
    for (int r = 0; r < 4; ++r) {
      int grow = m0 + wr * 64 + m * 16 + crow + r;
      if (grow < ce) {
        unsigned short* yr = Yb + (size_t)(base + grow) * DDIM + n0 + wc * 64 + ccol;
#pragma unroll
        for (int n = 0; n < 4; ++n)
          yr[n * 16] = f2bf(acc[m][n][r]);
      }
    }
  }
}

// ---------------- combine: out[t] = w0*Y[p0] + w1*Y[p1] ----------------
__global__ __launch_bounds__(256) void combine_kernel(
    const unsigned short* __restrict__ Yb, const int* __restrict__ tok_row,
    const float* __restrict__ w_of, float* __restrict__ out) {
  int t = blockIdx.x;
  int d = threadIdx.x * 4;
  int p0 = tok_row[2 * t], p1 = tok_row[2 * t + 1];
  float w0 = w_of[2 * t], w1 = w_of[2 * t + 1];
  ushort4 y0 = reinterpret_cast<const ushort4*>(Yb + (size_t)p0 * DDIM + d)[0];
  ushort4 y1 = reinterpret_cast<const ushort4*>(Yb + (size_t)p1 * DDIM + d)[0];
  float4 o;
  o.x = w0 * bf2f(y0.x) + w1 * bf2f(y1.x);
  o.y = w0 * bf2f(y0.y) + w1 * bf2f(y1.y);
  o.z = w0 * bf2f(y0.z) + w1 * bf2f(y1.z);
  o.w = w0 * bf2f(y0.w) + w1 * bf2f(y1.w);
  reinterpret_cast<float4*>(out + (size_t)t * DDIM + d)[0] = o;
}

extern "C" void kernel_launch(void* const* d_in, const int* in_sizes, int n_in,
                              void* d_out, int out_size, void* d_ws, size_t ws_size,
                              hipStream_t stream) {
  const float* x  = (const float*)d_in[0];
  const float* gw = (const float*)d_in[1];
  const float* ew = (const float*)d_in[2];
  float* out = (float*)d_out;
  char* ws = (char*)d_ws;

  unsigned short* xb = (unsigned short*)(ws);                    // 16 MB
  unsigned short* Wb = (unsigned short*)(ws + 16777216);         // 16 MB
  unsigned short* Yb = (unsigned short*)(ws + 33554432);         // 32 MB
  int*   e_of    = (int*)  (ws + 67108864);
  float* w_of    = (float*)(ws + 67174400);
  int*   row_src = (int*)  (ws + 67239936);
  int*   tok_row = (int*)  (ws + 67305472);
  int*   counts  = (int*)  (ws + 67371008);
  int*   offs    = (int*)  (ws + 67371040);
  int*   cursor  = (int*)  (ws + 67371072);
  int*   nblk    = (int*)  (ws + 67371104);
  int*   blkmap  = (int*)  (ws + 67371264);

  hipMemsetAsync(counts, 0, 32, stream);

  prep_kernel<<<10240, 256, 0, stream>>>(x, gw, ew, xb, Wb, e_of, w_of);
  count_kernel<<<32, 512, 0, stream>>>(e_of, counts);
  scan_kernel<<<1, 64, 0, stream>>>(counts, offs, cursor, nblk, blkmap);
  build_kernel<<<32, 256, 0, stream>>>(e_of, cursor, row_src, tok_row);

  gemm_kernel<<<1080, 256, 0, stream>>>(xb, Wb, row_src, counts, offs, nblk, blkmap, Yb);

  combine_kernel<<<T_TOK, 256, 0, stream>>>(Yb, tok_row, w_of, out);
}

// Round 9
// 107.275 us; speedup vs baseline: 1.0084x; 1.0084x over previous
//
#include <hip/hip_runtime.h>
#include <hip/hip_bf16.h>

#define T_TOK 8192
#define DDIM  1024
#define NEXP  8
#define NT    32   // K-tiles of 32

typedef __attribute__((ext_vector_type(8))) short bf16x8;
typedef __attribute__((ext_vector_type(4))) float f32x4;

__device__ inline unsigned short f2bf(float f) {
  union { float f; unsigned int u; } a; a.f = f;
  unsigned int u = a.u;
  unsigned int r = (u + 0x7fffu + ((u >> 16) & 1u)) >> 16;  // RNE
  return (unsigned short)r;
}

__device__ inline float bf2f(unsigned short u) {
  union { unsigned int u; float f; } a; a.u = ((unsigned int)u) << 16;
  return a.f;
}

__device__ inline void gload_lds16(const void* g, void* l) {
  __builtin_amdgcn_global_load_lds(
      (const __attribute__((address_space(1))) void*)g,
      (__attribute__((address_space(3))) void*)l, 16, 0, 0);
}

// ---------------- fused prep: blocks [0,2048) gate+cast-x, [2048,10240) cast W --
__global__ __launch_bounds__(256) void prep_kernel(
    const float* __restrict__ x, const float* __restrict__ gw,
    const float* __restrict__ ew,
    unsigned short* __restrict__ xb, unsigned short* __restrict__ Wb,
    int* __restrict__ e_of, float* __restrict__ w_of) {
  if (blockIdx.x >= 2048) {
    int i = (blockIdx.x - 2048) * 256 + threadIdx.x;   // < 2097152
    float4 v = reinterpret_cast<const float4*>(ew)[i];
    ushort4 o;
    o.x = f2bf(v.x); o.y = f2bf(v.y); o.z = f2bf(v.z); o.w = f2bf(v.w);
    reinterpret_cast<ushort4*>(Wb)[i] = o;
    return;
  }
  int t = blockIdx.x * 4 + (threadIdx.x >> 6);
  int lane = threadIdx.x & 63;
  const float4* xr = reinterpret_cast<const float4*>(x + (size_t)t * DDIM);
  ushort4* xbr = reinterpret_cast<ushort4*>(xb + (size_t)t * DDIM);
  float acc[NEXP];
#pragma unroll
  for (int e = 0; e < NEXP; ++e) acc[e] = 0.f;
#pragma unroll
  for (int c = 0; c < 4; ++c) {
    float4 xv = xr[c * 64 + lane];
    ushort4 o;
    o.x = f2bf(xv.x); o.y = f2bf(xv.y); o.z = f2bf(xv.z); o.w = f2bf(xv.w);
    xbr[c * 64 + lane] = o;
#pragma unroll
    for (int e = 0; e < NEXP; ++e) {
      float4 g = reinterpret_cast<const float4*>(gw + e * DDIM)[c * 64 + lane];
      acc[e] += xv.x * g.x + xv.y * g.y + xv.z * g.z + xv.w * g.w;
    }
  }
#pragma unroll
  for (int e = 0; e < NEXP; ++e) {
#pragma unroll
    for (int s = 32; s > 0; s >>= 1) acc[e] += __shfl_xor(acc[e], s);
  }
  if (lane == 0) {
    int e0 = 0; float v0 = acc[0];
#pragma unroll
    for (int e = 1; e < NEXP; ++e) if (acc[e] > v0) { v0 = acc[e]; e0 = e; }
    int e1 = (e0 == 0) ? 1 : 0; float v1 = acc[e1];
#pragma unroll
    for (int e = 0; e < NEXP; ++e)
      if (e != e0 && acc[e] > v1) { v1 = acc[e]; e1 = e; }
    float w1 = 1.f / (1.f + expf(v0 - v1));
    float w0 = 1.f - w1;
    e_of[2 * t] = e0; e_of[2 * t + 1] = e1;
    w_of[2 * t] = w0; w_of[2 * t + 1] = w1;
  }
}

// ---------------- counts: LDS histogram, 8 global atomics per block ----------------
__global__ __launch_bounds__(512) void count_kernel(
    const int* __restrict__ e_of, int* __restrict__ counts) {
  __shared__ int lc[NEXP];
  int tid = threadIdx.x;
  if (tid < NEXP) lc[tid] = 0;
  __syncthreads();
  atomicAdd(&lc[e_of[blockIdx.x * 512 + tid]], 1);
  __syncthreads();
  if (tid < NEXP) atomicAdd(&counts[tid], lc[tid]);
}

// ---------------- scan + block map (BM = 128) ----------------
__global__ void scan_kernel(const int* __restrict__ counts,
                            int* __restrict__ offs, int* __restrict__ cursor,
                            int* __restrict__ nblk, int* __restrict__ blkmap) {
  if (threadIdx.x == 0) {
    int s = 0;
    for (int e = 0; e < NEXP; ++e) { offs[e] = s; cursor[e] = s; s += counts[e]; }
    int nb = 0;
    for (int e = 0; e < NEXP; ++e) {
      int mb = (counts[e] + 127) >> 7;
      for (int j = 0; j < mb; ++j) blkmap[nb++] = (e << 8) | j;
    }
    nblk[0] = nb;
  }
}

// ---------------- build row lists: block-aggregated cursor atomics ----------------
__global__ __launch_bounds__(256) void build_kernel(
    const int* __restrict__ e_of, int* __restrict__ cursor,
    int* __restrict__ row_src, int* __restrict__ tok_row) {
  __shared__ int lc[NEXP];
  __shared__ int lbase[NEXP];
  int tid = threadIdx.x;
  if (tid < NEXP) lc[tid] = 0;
  __syncthreads();
  int i0 = blockIdx.x * 512 + tid;
  int i1 = i0 + 256;
  int ea = e_of[i0], eb = e_of[i1];
  int ra = atomicAdd(&lc[ea], 1);
  int rb = atomicAdd(&lc[eb], 1);
  __syncthreads();
  if (tid < NEXP) lbase[tid] = atomicAdd(&cursor[tid], lc[tid]);
  __syncthreads();
  int pa = lbase[ea] + ra;
  int pb = lbase[eb] + rb;
  row_src[pa] = i0 >> 1;
  tok_row[i0] = pa;
  row_src[pb] = i1 >> 1;
  tok_row[i1] = pb;
}

// ---------------- grouped GEMM: 128x128 tile, BK=32, 4 waves (2Mx2N) ------------
// Pipeline (R8-proven race-free): dbuf ring, issue tile t+1, s_waitcnt vmcnt(4)
// (own tile-t loads done), s_barrier (=> ALL waves' t-loads done), compute,
// barrier. 32 KB LDS -> 4 blocks/CU.
// LDS geometry: logical 128x32 stored as physical [64 prows][64 shorts]
// (128B rows => row term ≡ 0 mod 32 banks — the R7 measured-0-conflict
// pattern). Logical (r,c 16B-chunk): prow=r>>1, slot=((r&1)*4+c)^(prow&7).
// Stage: linear gload_lds dest; per-lane GLOBAL source carries the inverse:
// lane l -> s_log=(l&7)^(l>>3), row+=2*(l>>3)+(s_log>>2), col=(s_log&3)*8.
__global__ __launch_bounds__(256, 4) void gemm_kernel(
    const unsigned short* __restrict__ xb, const unsigned short* __restrict__ Wb,
    const int* __restrict__ row_src, const int* __restrict__ counts,
    const int* __restrict__ offs, const int* __restrict__ nblk,
    const int* __restrict__ blkmap, unsigned short* __restrict__ Yb) {
  // bijective XCD swizzle: 1080 = 8 * 135; consecutive wg share one XCD's L2.
  int orig = blockIdx.x;
  int wg = (orig & 7) * 135 + (orig >> 3);
  int mi = wg >> 3, ni = wg & 7;
  if (mi >= nblk[0]) return;
  int em = blkmap[mi];
  int e = em >> 8, mj = em & 255;
  int ce = counts[e];
  int base = offs[e];
  int m0 = mj << 7;    // 128-row m-block
  int n0 = ni << 7;    // 128-col n-block

  __shared__ unsigned short As[2][64 * 64];  // 16 KB (phys 64 prows x 128B)
  __shared__ unsigned short Bs[2][64 * 64];  // 16 KB

  int tid = threadIdx.x;
  int lane = tid & 63;
  int wid = tid >> 6;          // 0..3
  int wr = wid >> 1, wc = wid & 1;   // 2(M) x 2(N), wave tile 64x64

  // staging lane decode: chunk = 8 prows = 16 logical rows = 1024 B
  int sl = lane & 7;                 // phys slot
  int pr = lane >> 3;                // prow within chunk
  int s_log = sl ^ pr;
  int rloc = pr * 2 + (s_log >> 2);  // logical row within 16-row chunk
  int cel = (s_log & 3) * 8;         // element offset within BK=32

  const unsigned short* We = Wb + (size_t)e * DDIM * DDIM;
  const unsigned short* asrc[2];
  const unsigned short* bsrc[2];
#pragma unroll
  for (int j = 0; j < 2; ++j) {
    int row = (wid * 2 + j) * 16 + rloc;   // [0,128)
    int i = m0 + row; if (i > ce - 1) i = ce - 1;
    int tk = row_src[base + i];
    asrc[j] = xb + (size_t)tk * DDIM + cel;
    bsrc[j] = We + (size_t)(n0 + row) * DDIM + cel;
  }

  f32x4 acc[4][4];
#pragma unroll
  for (int m = 0; m < 4; ++m)
#pragma unroll
    for (int n = 0; n < 4; ++n) acc[m][n] = (f32x4){0.f, 0.f, 0.f, 0.f};

  int lrow_a = wr * 64 + (lane & 15);
  int lrow_b = wc * 64 + (lane & 15);
  int fc = lane >> 4;                // 0..3 logical 16B k-chunk
  int rpar4 = (lane & 1) << 2;       // (r&1)*4, constant per lane

  // prologue: stage tile 0 -> buf0 (4 loads/wave)
#pragma unroll
  for (int j = 0; j < 2; ++j) {
    gload_lds16(asrc[j], &As[0][(wid * 2 + j) * 512]);
    gload_lds16(bsrc[j], &Bs[0][(wid * 2 + j) * 512]);
  }

  for (int t = 0; t < NT; ++t) {
    int b = t & 1;
    if (t + 1 < NT) {
      int koff = (t + 1) * 32;
      unsigned short* Ad = &As[b ^ 1][0];
      unsigned short* Bd = &Bs[b ^ 1][0];
#pragma unroll
      for (int j = 0; j < 2; ++j) {
        gload_lds16(asrc[j] + koff, Ad + (wid * 2 + j) * 512);
        gload_lds16(bsrc[j] + koff, Bd + (wid * 2 + j) * 512);
      }
      asm volatile("s_waitcnt vmcnt(4)" ::: "memory");  // own tile-t loads done
    } else {
      asm volatile("s_waitcnt vmcnt(0)" ::: "memory");  // final drain
    }
    __builtin_amdgcn_s_barrier();   // => ALL waves' tile-t loads done
    asm volatile("" ::: "memory");

    const unsigned short* Ar = &As[b][0];
    const unsigned short* Br = &Bs[b][0];
    bf16x8 af[4], bfr[4];
#pragma unroll
    for (int m = 0; m < 4; ++m) {
      int r = lrow_a + m * 16;
      int prow = r >> 1;
      int s = (rpar4 + fc) ^ (prow & 7);
      af[m] = *reinterpret_cast<const bf16x8*>(&Ar[prow * 64 + s * 8]);
    }
#pragma unroll
    for (int n = 0; n < 4; ++n) {
      int r = lrow_b + n * 16;
      int prow = r >> 1;
      int s = (rpar4 + fc) ^ (prow & 7);
      bfr[n] = *reinterpret_cast<const bf16x8*>(&Br[prow * 64 + s * 8]);
    }
    __builtin_amdgcn_s_setprio(1);
#pragma unroll
    for (int m = 0; m < 4; ++m)
#pragma unroll
      for (int n = 0; n < 4; ++n)
        acc[m][n] = __builtin_amdgcn_mfma_f32_16x16x32_bf16(af[m], bfr[n], acc[m][n], 0, 0, 0);
    __builtin_amdgcn_s_setprio(0);

    asm volatile("" ::: "memory");
    __builtin_amdgcn_s_barrier();   // all waves done reading buf b
  }

  // epilogue: C/D layout col=lane&15, row=(lane>>4)*4+reg
  int crow = (lane >> 4) * 4;
  int ccol = lane & 15;
#pragma unroll
  for (int m = 0; m < 4; ++m) {
#pragma unroll
    for (int r = 0; r < 4; ++r) {
      int grow = m0 + wr * 64 + m * 16 + crow + r;
      if (grow < ce) {
        unsigned short* yr = Yb + (size_t)(base + grow) * DDIM + n0 + wc * 64 + ccol;
#pragma unroll
        for (int n = 0; n < 4; ++n)
          yr[n * 16] = f2bf(acc[m][n][r]);
      }
    }
  }
}

// ---------------- combine: out[t] = w0*Y[p0] + w1*Y[p1] ----------------
__global__ __launch_bounds__(256) void combine_kernel(
    const unsigned short* __restrict__ Yb, const int* __restrict__ tok_row,
    const float* __restrict__ w_of, float* __restrict__ out) {
  int t = blockIdx.x;
  int d = threadIdx.x * 4;
  int p0 = tok_row[2 * t], p1 = tok_row[2 * t + 1];
  float w0 = w_of[2 * t], w1 = w_of[2 * t + 1];
  ushort4 y0 = reinterpret_cast<const ushort4*>(Yb + (size_t)p0 * DDIM + d)[0];
  ushort4 y1 = reinterpret_cast<const ushort4*>(Yb + (size_t)p1 * DDIM + d)[0];
  float4 o;
  o.x = w0 * bf2f(y0.x) + w1 * bf2f(y1.x);
  o.y = w0 * bf2f(y0.y) + w1 * bf2f(y1.y);
  o.z = w0 * bf2f(y0.z) + w1 * bf2f(y1.z);
  o.w = w0 * bf2f(y0.w) + w1 * bf2f(y1.w);
  reinterpret_cast<float4*>(out + (size_t)t * DDIM + d)[0] = o;
}

extern "C" void kernel_launch(void* const* d_in, const int* in_sizes, int n_in,
                              void* d_out, int out_size, void* d_ws, size_t ws_size,
                              hipStream_t stream) {
  const float* x  = (const float*)d_in[0];
  const float* gw = (const float*)d_in[1];
  const float* ew = (const float*)d_in[2];
  float* out = (float*)d_out;
  char* ws = (char*)d_ws;

  unsigned short* xb = (unsigned short*)(ws);                    // 16 MB
  unsigned short* Wb = (unsigned short*)(ws + 16777216);         // 16 MB
  unsigned short* Yb = (unsigned short*)(ws + 33554432);         // 32 MB
  int*   e_of    = (int*)  (ws + 67108864);
  float* w_of    = (float*)(ws + 67174400);
  int*   row_src = (int*)  (ws + 67239936);
  int*   tok_row = (int*)  (ws + 67305472);
  int*   counts  = (int*)  (ws + 67371008);
  int*   offs    = (int*)  (ws + 67371040);
  int*   cursor  = (int*)  (ws + 67371072);
  int*   nblk    = (int*)  (ws + 67371104);
  int*   blkmap  = (int*)  (ws + 67371264);

  hipMemsetAsync(counts, 0, 32, stream);

  prep_kernel<<<10240, 256, 0, stream>>>(x, gw, ew, xb, Wb, e_of, w_of);
  count_kernel<<<32, 512, 0, stream>>>(e_of, counts);
  scan_kernel<<<1, 64, 0, stream>>>(counts, offs, cursor, nblk, blkmap);
  build_kernel<<<32, 256, 0, stream>>>(e_of, cursor, row_src, tok_row);

  gemm_kernel<<<1080, 256, 0, stream>>>(xb, Wb, row_src, counts, offs, nblk, blkmap, Yb);

  combine_kernel<<<T_TOK, 256, 0, stream>>>(Yb, tok_row, w_of, out);
}